// Round 4
// baseline (1455.681 us; speedup 1.0000x reference)
//
#include <hip/hip_runtime.h>
#include <hip/hip_bf16.h>
#include <stdint.h>

typedef __hip_bfloat16 bf16;

#define NVOCAB 113
#define NPAIR (113 * 113)   // 12769
#define DDIM 128
#define HIDDIM 512

// canonical fp32 weight pool element offsets (11 tensors)
#define OFF_TOK 0
#define OFF_POS 14464
#define OFF_WQ  14720
#define OFF_WK  31104
#define OFF_WV  47488
#define OFF_WO  63872
#define OFF_W1  80256
#define OFF_B1  145792
#define OFF_W2  146304
#define OFF_B2  211840
#define OFF_WU  211968
#define WTOTAL  226432

// ---------------- runtime dtype detection ----------------
// flags[0]: 1 if float tensors are bf16 (else fp32)
// flags[1]: 1 if x is int64 (else int32)
__global__ void detect_kernel(const uint32_t* __restrict__ tok_raw,
                              const uint32_t* __restrict__ x_raw,
                              int* __restrict__ flags) {
  __shared__ int cnt_bf16, cnt_xnz;
  if (threadIdx.x == 0) { cnt_bf16 = 0; cnt_xnz = 0; }
  __syncthreads();
  // bf16 test: low 16 bits of dword are a plausible small-normal bf16?
  uint32_t u = tok_raw[threadIdx.x];
  int e = (u >> 7) & 0xff;
  if (e >= 100 && e <= 126) atomicAdd(&cnt_bf16, 1);
  // int64 test: odd dwords are high words (all zero) under int64
  uint32_t xv = x_raw[2 * threadIdx.x + 1];
  if (xv != 0u) atomicAdd(&cnt_xnz, 1);
  __syncthreads();
  if (threadIdx.x == 0) {
    flags[0] = (cnt_bf16 >= 128) ? 1 : 0;
    flags[1] = (cnt_xnz == 0) ? 1 : 0;
  }
}

// ---------------- canonicalize all float tensors to fp32 pool ----------------
struct SrcPtrs { const void* p[11]; };

__global__ void convert_kernel(SrcPtrs sp, float* __restrict__ dst,
                               const int* __restrict__ flags) {
  const int idx = blockIdx.x * 256 + threadIdx.x;
  if (idx >= WTOTAL) return;
  const int pref[12] = {OFF_TOK, OFF_POS, OFF_WQ, OFF_WK, OFF_WV, OFF_WO,
                        OFF_W1, OFF_B1, OFF_W2, OFF_B2, OFF_WU, WTOTAL};
  int t = 0;
  while (idx >= pref[t + 1]) ++t;
  const int local = idx - pref[t];
  const void* src = sp.p[t];
  if (flags[0]) {
    dst[idx] = __bfloat162float(((const bf16*)src)[local]);  // exact widen
  } else {
    dst[idx] = ((const float*)src)[local];                   // identity
  }
}

// ---------------- Phase A: per-(token,pos) embeddings + q/k/v ----------------
// grid: 226 blocks (row = t*2 + p), 128 threads
__global__ void qkv_kernel(const float* __restrict__ wf,
                           float* __restrict__ resid_pre,
                           float* __restrict__ qt,
                           float* __restrict__ kt,
                           float* __restrict__ vt) {
  const float* tok_emb = wf + OFF_TOK;
  const float* pos_emb = wf + OFF_POS;
  const float* W_Q = wf + OFF_WQ;
  const float* W_K = wf + OFF_WK;
  const float* W_V = wf + OFF_WV;

  const int row = blockIdx.x;          // t*2 + p
  const int t = row >> 1, p = row & 1;
  const int tid = threadIdx.x;         // 0..127

  __shared__ float r[DDIM];
  float rv = tok_emb[t * DDIM + tid] + pos_emb[p * DDIM + tid];
  r[tid] = rv;
  resid_pre[row * DDIM + tid] = rv;
  __syncthreads();

  // output element tid = h*32 + j ;  W_Q[h][d][j] at h*4096 + d*32 + j
  const int h = tid >> 5, j = tid & 31;
  const float* wq = W_Q + h * 4096 + j;
  const float* wk = W_K + h * 4096 + j;
  const float* wv = W_V + h * 4096 + j;
  float aq = 0.f, ak = 0.f, av = 0.f;
  #pragma unroll 4
  for (int d = 0; d < DDIM; ++d) {
    float rd = r[d];
    aq += rd * wq[d * 32];
    ak += rd * wk[d * 32];
    av += rd * wv[d * 32];
  }
  qt[row * DDIM + tid] = aq;
  kt[row * DDIM + tid] = ak;
  vt[row * DDIM + tid] = av;
}

// ---------------- Phase B: one block per (t0,t1) pair ----------------
// grid: 12769 blocks, 256 threads
__global__ void __launch_bounds__(256) pair_kernel(
    const float* __restrict__ resid_pre, const float* __restrict__ qt,
    const float* __restrict__ kt, const float* __restrict__ vt,
    const float* __restrict__ wf, float* __restrict__ table) {
  const float* W_O = wf + OFF_WO;
  const float* W1  = wf + OFF_W1;
  const float* b1  = wf + OFF_B1;
  const float* W2  = wf + OFF_W2;
  const float* b2  = wf + OFF_B2;
  const float* W_U = wf + OFF_WU;

  const int pair = blockIdx.x;
  const int t0 = pair / NVOCAB;
  const int t1 = pair - t0 * NVOCAB;
  const int row0 = t0 * 2;       // token t0 at position 0
  const int row1 = t1 * 2 + 1;   // token t1 at position 1
  const int tid = threadIdx.x;

  __shared__ float sr[2][DDIM], sq[2][DDIM], sk[2][DDIM], sv[2][DDIM];
  __shared__ float sz[2][DDIM], smid[2][DDIM], sres[2][DDIM];
  __shared__ float sh[2][HIDDIM];
  __shared__ float spat[16];

  // load the pair's activations (2 rows x 4 arrays x 128)
  {
    const int qp = tid >> 7, d = tid & 127;
    const int row = qp ? row1 : row0;
    sr[qp][d] = resid_pre[row * DDIM + d];
    sq[qp][d] = qt[row * DDIM + d];
    sk[qp][d] = kt[row * DDIM + d];
    sv[qp][d] = vt[row * DDIM + d];
  }
  __syncthreads();

  // scores: 16 = 4 heads x 2 qpos x 2 spos, dot over 32 dims
  if (tid < 16) {
    const int h = tid >> 2, qp = (tid >> 1) & 1, sp = tid & 1;
    float acc = 0.f;
    #pragma unroll
    for (int j = 0; j < 32; ++j) acc += sq[qp][h * 32 + j] * sk[sp][h * 32 + j];
    spat[tid] = acc * 0.17677669529663687f;  // 1/sqrt(32)
  }
  __syncthreads();

  // softmax over spos, then blend: 0.5 + 0.5*p
  if (tid < 8) {
    const int base = tid * 2;  // (h,qp) -> slots base, base+1
    float s0 = spat[base], s1 = spat[base + 1];
    float m = fmaxf(s0, s1);
    float e0 = __expf(s0 - m), e1 = __expf(s1 - m);
    float inv = 1.f / (e0 + e1);
    spat[base]     = 0.5f + 0.5f * e0 * inv;
    spat[base + 1] = 0.5f + 0.5f * e1 * inv;
  }
  __syncthreads();

  // z[qp][c] = pat[h,qp,0]*v0[c] + pat[h,qp,1]*v1[c],  h = c>>5
  {
    const int qp = tid >> 7, c = tid & 127, h = c >> 5;
    sz[qp][c] = spat[h * 4 + qp * 2] * sv[0][c] + spat[h * 4 + qp * 2 + 1] * sv[1][c];
  }
  __syncthreads();

  // attn_out + residual:  W_O flattened [hk=128][d=128]
  {
    const int qp = tid >> 7, c = tid & 127;
    float acc = sr[qp][c];
    #pragma unroll 4
    for (int cc = 0; cc < DDIM; ++cc)
      acc += sz[qp][cc] * W_O[cc * DDIM + c];
    smid[qp][c] = acc;
  }
  __syncthreads();

  // MLP hidden: 1024 outputs (2 x 512), float2 weight loads
  for (int it = tid; it < 512; it += 256) {
    const int qp = it >> 8, jp = it & 255, j = jp * 2;
    float a0 = b1[j], a1 = b1[j + 1];
    const float2* wrow = (const float2*)W1 + jp;  // row d: float2 d*256 + jp
    #pragma unroll 4
    for (int d = 0; d < DDIM; ++d) {
      float2 w = wrow[d * 256];
      float r = smid[qp][d];
      a0 += r * w.x;
      a1 += r * w.y;
    }
    sh[qp][j]     = fmaxf(a0, 0.f);
    sh[qp][j + 1] = fmaxf(a1, 0.f);
  }
  __syncthreads();

  // second MLP layer + residual; split j-range across lane pairs
  {
    const int qp = tid >> 7, rest = tid & 127;
    const int cp = rest >> 1, jh = rest & 1;  // cp: column pair, jh: j-half
    const int c = cp * 2;
    float a0 = 0.f, a1 = 0.f;
    const float2* w2 = (const float2*)W2 + cp;  // row j: float2 j*64 + cp
    const int j0 = jh * 256;
    #pragma unroll 4
    for (int j = j0; j < j0 + 256; ++j) {
      float2 w = w2[j * 64];
      float hv = sh[qp][j];
      a0 += hv * w.x;
      a1 += hv * w.y;
    }
    a0 += __shfl_xor(a0, 1);
    a1 += __shfl_xor(a1, 1);
    if (jh == 0) {
      sres[qp][c]     = smid[qp][c] + b2[c] + a0;
      sres[qp][c + 1] = smid[qp][c + 1] + b2[c + 1] + a1;
    }
  }
  __syncthreads();

  // unembed: 226 outputs (2 x 113), store fp32 table row
  for (int o = tid; o < 226; o += 256) {
    const int oq = o / NVOCAB, vv = o - oq * NVOCAB;
    const float2* wu = (const float2*)W_U + vv * 64;
    float a = 0.f;
    #pragma unroll 4
    for (int dp = 0; dp < 64; ++dp) {
      float2 w = wu[dp];
      a += sres[oq][dp * 2] * w.x;
      a += sres[oq][dp * 2 + 1] * w.y;
    }
    table[pair * 226 + o] = a;
  }
}

// ---------------- Phase C: gather table rows into fp32 output ----------------
// out row b = table row (x[b][0]*113 + x[b][1]); rows are 226 fp32 = 113 float2
__global__ void gather_kernel(const uint32_t* __restrict__ x_raw,
                              const float2* __restrict__ table_v2,
                              float2* __restrict__ out_v2, int total,
                              const int* __restrict__ flags) {
  __shared__ int is64;
  if (threadIdx.x == 0) is64 = flags[1];
  __syncthreads();
  const int i = blockIdx.x * blockDim.x + threadIdx.x;
  if (i >= total) return;
  const int b = i / NVOCAB;
  const int j = i - b * NVOCAB;
  int t0, t1;
  if (is64) {  // int64 little-endian: element k's low dword at 2k
    t0 = (int)x_raw[4 * b];
    t1 = (int)x_raw[4 * b + 2];
  } else {
    t0 = (int)x_raw[2 * b];
    t1 = (int)x_raw[2 * b + 1];
  }
  t0 = min(max(t0, 0), NVOCAB - 1);
  t1 = min(max(t1, 0), NVOCAB - 1);
  const int pair = t0 * NVOCAB + t1;
  out_v2[i] = table_v2[pair * NVOCAB + j];
}

extern "C" void kernel_launch(void* const* d_in, const int* in_sizes, int n_in,
                              void* d_out, int out_size, void* d_ws, size_t ws_size,
                              hipStream_t stream) {
  // ws layout (byte offsets, aligned)
  int*   flags     = (int*)d_ws;                           // 2 ints
  float* wf        = (float*)((char*)d_ws + 256);          // 226432 f32 = 905728 B
  float* resid_pre = (float*)((char*)d_ws + 905984);       // 226*128 f32
  float* qt        = (float*)((char*)d_ws + 1021696);
  float* kt        = (float*)((char*)d_ws + 1137408);
  float* vt        = (float*)((char*)d_ws + 1253120);
  float* table     = (float*)((char*)d_ws + 1368832);      // 12769*226 f32 (~11.5 MB)

  const int B = in_sizes[0] / 2;

  detect_kernel<<<1, 256, 0, stream>>>((const uint32_t*)d_in[1],
                                       (const uint32_t*)d_in[0], flags);

  SrcPtrs sp;
  for (int i = 0; i < 11; ++i) sp.p[i] = d_in[i + 1];
  convert_kernel<<<(WTOTAL + 255) / 256, 256, 0, stream>>>(sp, wf, flags);

  qkv_kernel<<<226, 128, 0, stream>>>(wf, resid_pre, qt, kt, vt);
  pair_kernel<<<NPAIR, 256, 0, stream>>>(resid_pre, qt, kt, vt, wf, table);

  const int total = B * NVOCAB;  // float2 elements in output
  gather_kernel<<<(total + 255) / 256, 256, 0, stream>>>(
      (const uint32_t*)d_in[0], (const float2*)table, (float2*)d_out,
      total, flags);
}

// Round 5
// 279.432 us; speedup vs baseline: 5.2094x; 5.2094x over previous
//
#include <hip/hip_runtime.h>
#include <hip/hip_bf16.h>
#include <stdint.h>

typedef __hip_bfloat16 bf16;
typedef __attribute__((ext_vector_type(8))) short short8;
typedef __attribute__((ext_vector_type(4))) float float4v;

#define NVOCAB 113
#define NPAIR (113 * 113)   // 12769
#define DDIM 128
#define HIDDIM 512

// canonical fp32 weight pool element offsets (11 tensors)
#define OFF_TOK 0
#define OFF_POS 14464
#define OFF_WQ  14720
#define OFF_WK  31104
#define OFF_WV  47488
#define OFF_WO  63872
#define OFF_W1  80256
#define OFF_B1  145792
#define OFF_W2  146304
#define OFF_B2  211840
#define OFF_WU  211968
#define WTOTAL  226432

// bf16 transposed weight pool (element offsets within wb)
#define BOFF_WOT 0                         // WOT[d][hk] = W_O[hk][d]     128x128
#define BOFF_W1T 16384                     // W1T[n][d]  = W1[d][n]       512x128
#define BOFF_W2T (16384 + 65536)           // W2T[d][j]  = W2[j][d]       128x512
#define BOFF_WUP (16384 + 65536 + 65536)   // WUP[v][d]  = W_U[v][d]|0    128x128 (pad v>=113)
#define BTOTAL   (16384 + 65536 + 65536 + 16384)  // 163840

__device__ __forceinline__ uint16_t f2b(float f) {
  bf16 h = __float2bfloat16(f);
  return *(uint16_t*)&h;
}

// ---------------- runtime dtype detection ----------------
__global__ void detect_kernel(const uint32_t* __restrict__ tok_raw,
                              const uint32_t* __restrict__ x_raw,
                              int* __restrict__ flags) {
  __shared__ int cnt_bf16, cnt_xnz;
  if (threadIdx.x == 0) { cnt_bf16 = 0; cnt_xnz = 0; }
  __syncthreads();
  uint32_t u = tok_raw[threadIdx.x];
  int e = (u >> 7) & 0xff;
  if (e >= 100 && e <= 126) atomicAdd(&cnt_bf16, 1);
  uint32_t xv = x_raw[2 * threadIdx.x + 1];
  if (xv != 0u) atomicAdd(&cnt_xnz, 1);
  __syncthreads();
  if (threadIdx.x == 0) {
    flags[0] = (cnt_bf16 >= 128) ? 1 : 0;   // float tensors are bf16
    flags[1] = (cnt_xnz == 0) ? 1 : 0;      // x is int64
  }
}

// ---------------- canonicalize all float tensors to fp32 pool ----------------
struct SrcPtrs { const void* p[11]; };

__global__ void convert_kernel(SrcPtrs sp, float* __restrict__ dst,
                               const int* __restrict__ flags) {
  const int idx = blockIdx.x * 256 + threadIdx.x;
  if (idx >= WTOTAL) return;
  const int pref[12] = {OFF_TOK, OFF_POS, OFF_WQ, OFF_WK, OFF_WV, OFF_WO,
                        OFF_W1, OFF_B1, OFF_W2, OFF_B2, OFF_WU, WTOTAL};
  int t = 0;
  while (idx >= pref[t + 1]) ++t;
  const int local = idx - pref[t];
  const void* src = sp.p[t];
  if (flags[0]) {
    dst[idx] = __bfloat162float(((const bf16*)src)[local]);
  } else {
    dst[idx] = ((const float*)src)[local];
  }
}

// ---------------- build bf16 transposed weights for MFMA B-operands ----------
__global__ void transpose_bf16_kernel(const float* __restrict__ wf,
                                      uint16_t* __restrict__ wb) {
  const int idx = blockIdx.x * 256 + threadIdx.x;
  if (idx >= BTOTAL) return;
  float v;
  if (idx < BOFF_W1T) {                       // WOT[d][c] = W_O[c*128+d]
    int l = idx, d = l >> 7, c = l & 127;
    v = wf[OFF_WO + c * 128 + d];
  } else if (idx < BOFF_W2T) {                // W1T[n][d] = W1[d*512+n]
    int l = idx - BOFF_W1T, n = l >> 7, d = l & 127;
    v = wf[OFF_W1 + d * 512 + n];
  } else if (idx < BOFF_WUP) {                // W2T[d][j] = W2[j*128+d]
    int l = idx - BOFF_W2T, d = l >> 9, j = l & 511;
    v = wf[OFF_W2 + j * 128 + d];
  } else {                                    // WUP[v][d] = W_U[v*128+d] or 0
    int l = idx - BOFF_WUP, vv = l >> 7, d = l & 127;
    v = (vv < NVOCAB) ? wf[OFF_WU + vv * 128 + d] : 0.f;
  }
  wb[idx] = f2b(v);
}

// ---------------- Phase A: per-(token,pos) embeddings + q/k/v ----------------
__global__ void qkv_kernel(const float* __restrict__ wf,
                           float* __restrict__ resid_pre,
                           float* __restrict__ qt,
                           float* __restrict__ kt,
                           float* __restrict__ vt) {
  const float* tok_emb = wf + OFF_TOK;
  const float* pos_emb = wf + OFF_POS;
  const float* W_Q = wf + OFF_WQ;
  const float* W_K = wf + OFF_WK;
  const float* W_V = wf + OFF_WV;

  const int row = blockIdx.x;
  const int t = row >> 1, p = row & 1;
  const int tid = threadIdx.x;

  __shared__ float r[DDIM];
  float rv = tok_emb[t * DDIM + tid] + pos_emb[p * DDIM + tid];
  r[tid] = rv;
  resid_pre[row * DDIM + tid] = rv;
  __syncthreads();

  const int h = tid >> 5, j = tid & 31;
  const float* wq = W_Q + h * 4096 + j;
  const float* wk = W_K + h * 4096 + j;
  const float* wv = W_V + h * 4096 + j;
  float aq = 0.f, ak = 0.f, av = 0.f;
  #pragma unroll 4
  for (int d = 0; d < DDIM; ++d) {
    float rd = r[d];
    aq += rd * wq[d * 32];
    ak += rd * wk[d * 32];
    av += rd * wv[d * 32];
  }
  qt[row * DDIM + tid] = aq;
  kt[row * DDIM + tid] = ak;
  vt[row * DDIM + tid] = av;
}

// ---------------- Phase B: fused MFMA kernel, 16 pairs (32 rows) / block ----
// A-staging LDS layout: bf16, rows of CHUNKS 16-byte chunks, chunk-XOR swizzle:
//   element [m][k] lives at (m*CHUNKS + ((k>>3) ^ (m&15)))*8 + (k&7)
// MFMA fragment maps (gfx950, 16x16x32 bf16):
//   A: lane holds A[m=lane&15][k=quad*8+j], j=0..7
//   B: lane holds B[k=quad*8+j][n=lane&15]
//   D: reg r = D[row=quad*4+r][col=lane&15]
__global__ void __launch_bounds__(256) pair_mfma_kernel(
    const float* __restrict__ resid_pre, const float* __restrict__ qt,
    const float* __restrict__ kt, const float* __restrict__ vt,
    const float* __restrict__ wf, const uint16_t* __restrict__ wb,
    float* __restrict__ table) {
  __shared__ uint16_t bufA[32 * 512];   // Z (K=128) then H (K=512)
  __shared__ uint16_t bufB[32 * 128];   // smid-bf16 then R-bf16
  __shared__ float    sF[32 * 128];     // resid fp32 -> smid fp32
  __shared__ float    spat[16 * 16];

  const int tid = threadIdx.x;
  const int blk = blockIdx.x;

  // ---- prologue: attention scores -> softmax blend -> Z, stage resid ----
  {
    const int pl = tid >> 4, s = tid & 15;
    const int pair = blk * 16 + pl;
    if (pair < NPAIR) {
      const int t0 = pair / NVOCAB, t1 = pair - t0 * NVOCAB;
      const int row0 = t0 * 2, row1 = t1 * 2 + 1;
      const int h = s >> 2, qp = (s >> 1) & 1, sp = s & 1;
      const float* qrow = qt + (qp ? row1 : row0) * DDIM + h * 32;
      const float* krow = kt + (sp ? row1 : row0) * DDIM + h * 32;
      float acc = 0.f;
      #pragma unroll
      for (int j = 0; j < 32; ++j) acc += qrow[j] * krow[j];
      spat[pl * 16 + s] = acc * 0.17677669529663687f;
    } else {
      spat[pl * 16 + s] = 0.f;
    }
  }
  __syncthreads();
  {
    const int pl = tid >> 4, s = tid & 15;
    if (s < 8) {
      float s0 = spat[pl * 16 + s * 2], s1 = spat[pl * 16 + s * 2 + 1];
      float m = fmaxf(s0, s1);
      float e0 = __expf(s0 - m), e1 = __expf(s1 - m);
      float inv = 1.f / (e0 + e1);
      spat[pl * 16 + s * 2]     = 0.5f + 0.5f * e0 * inv;
      spat[pl * 16 + s * 2 + 1] = 0.5f + 0.5f * e1 * inv;
    }
  }
  __syncthreads();
  {
    const int pl = tid >> 4, s = tid & 15;
    const int pair = blk * 16 + pl;
    const int qp = s >> 3, c0 = (s & 7) * 16;
    const int m = pl * 2 + qp;
    if (pair < NPAIR) {
      const int t0 = pair / NVOCAB, t1 = pair - t0 * NVOCAB;
      const int row0 = t0 * 2, row1 = t1 * 2 + 1;
      const int rowm = qp ? row1 : row0;
      for (int c = c0; c < c0 + 16; ++c) {
        const int h = c >> 5;
        float p0 = spat[pl * 16 + h * 4 + qp * 2];
        float p1 = spat[pl * 16 + h * 4 + qp * 2 + 1];
        float z = p0 * vt[row0 * DDIM + c] + p1 * vt[row1 * DDIM + c];
        bufA[(m * 16 + ((c >> 3) ^ (m & 15))) * 8 + (c & 7)] = f2b(z);
        sF[m * DDIM + c] = resid_pre[rowm * DDIM + c];
      }
    } else {
      for (int c = c0; c < c0 + 16; ++c) {
        bufA[(m * 16 + ((c >> 3) ^ (m & 15))) * 8 + (c & 7)] = 0;
        sF[m * DDIM + c] = 0.f;
      }
    }
  }
  __syncthreads();

  const int lane = tid & 63, w = tid >> 6;
  const int l15 = lane & 15, quad = lane >> 4;
  const int rowtile = w >> 1, npar = w & 1;
  const int mA = rowtile * 16 + l15;

  // ---- GEMM0: smid = Z x WOT + resid  (N=128, K=128) ----
  {
    short8 af[4];
    #pragma unroll
    for (int ks = 0; ks < 4; ++ks)
      af[ks] = *(const short8*)&bufA[(mA * 16 + ((ks * 4 + quad) ^ (mA & 15))) * 8];
    #pragma unroll
    for (int ni = 0; ni < 4; ++ni) {
      const int n = (npar + ni * 2) * 16 + l15;
      const uint16_t* bp = wb + BOFF_WOT + n * 128 + quad * 8;
      float4v acc = {0.f, 0.f, 0.f, 0.f};
      #pragma unroll
      for (int ks = 0; ks < 4; ++ks) {
        short8 bfv = *(const short8*)(bp + ks * 32);
        acc = __builtin_amdgcn_mfma_f32_16x16x32_bf16(af[ks], bfv, acc, 0, 0, 0);
      }
      #pragma unroll
      for (int r = 0; r < 4; ++r) {
        const int row = rowtile * 16 + quad * 4 + r;
        float v = acc[r] + sF[row * DDIM + n];
        sF[row * DDIM + n] = v;
        bufB[(row * 16 + ((n >> 3) ^ (row & 15))) * 8 + (n & 7)] = f2b(v);
      }
    }
  }
  __syncthreads();

  // ---- GEMM1: H = relu(smid x W1 + b1)  (N=512, K=128) ----
  {
    short8 af[4];
    #pragma unroll
    for (int ks = 0; ks < 4; ++ks)
      af[ks] = *(const short8*)&bufB[(mA * 16 + ((ks * 4 + quad) ^ (mA & 15))) * 8];
    #pragma unroll
    for (int ni = 0; ni < 16; ++ni) {
      const int n = (npar + ni * 2) * 16 + l15;
      const uint16_t* bp = wb + BOFF_W1T + n * 128 + quad * 8;
      float4v acc = {0.f, 0.f, 0.f, 0.f};
      #pragma unroll
      for (int ks = 0; ks < 4; ++ks) {
        short8 bfv = *(const short8*)(bp + ks * 32);
        acc = __builtin_amdgcn_mfma_f32_16x16x32_bf16(af[ks], bfv, acc, 0, 0, 0);
      }
      const float bias = wf[OFF_B1 + n];
      #pragma unroll
      for (int r = 0; r < 4; ++r) {
        const int row = rowtile * 16 + quad * 4 + r;
        float v = fmaxf(acc[r] + bias, 0.f);
        bufA[(row * 64 + ((n >> 3) ^ (row & 15))) * 8 + (n & 7)] = f2b(v);
      }
    }
  }
  __syncthreads();

  // ---- GEMM2: R = smid + H x W2 + b2  (N=128, K=512) ----
  {
    short8 af[16];
    #pragma unroll
    for (int ks = 0; ks < 16; ++ks)
      af[ks] = *(const short8*)&bufA[(mA * 64 + ((ks * 4 + quad) ^ (mA & 15))) * 8];
    #pragma unroll
    for (int ni = 0; ni < 4; ++ni) {
      const int n = (npar + ni * 2) * 16 + l15;
      const uint16_t* bp = wb + BOFF_W2T + n * 512 + quad * 8;
      float4v acc = {0.f, 0.f, 0.f, 0.f};
      #pragma unroll
      for (int ks = 0; ks < 16; ++ks) {
        short8 bfv = *(const short8*)(bp + ks * 32);
        acc = __builtin_amdgcn_mfma_f32_16x16x32_bf16(af[ks], bfv, acc, 0, 0, 0);
      }
      const float bias = wf[OFF_B2 + n];
      #pragma unroll
      for (int r = 0; r < 4; ++r) {
        const int row = rowtile * 16 + quad * 4 + r;
        float v = acc[r] + bias + sF[row * DDIM + n];
        bufB[(row * 16 + ((n >> 3) ^ (row & 15))) * 8 + (n & 7)] = f2b(v);
      }
    }
  }
  __syncthreads();

  // ---- GEMM3: logits = R x WUP^T  (N=128 padded, K=128) ----
  {
    short8 af[4];
    #pragma unroll
    for (int ks = 0; ks < 4; ++ks)
      af[ks] = *(const short8*)&bufB[(mA * 16 + ((ks * 4 + quad) ^ (mA & 15))) * 8];
    #pragma unroll
    for (int ni = 0; ni < 4; ++ni) {
      const int n = (npar + ni * 2) * 16 + l15;
      const uint16_t* bp = wb + BOFF_WUP + n * 128 + quad * 8;
      float4v acc = {0.f, 0.f, 0.f, 0.f};
      #pragma unroll
      for (int ks = 0; ks < 4; ++ks) {
        short8 bfv = *(const short8*)(bp + ks * 32);
        acc = __builtin_amdgcn_mfma_f32_16x16x32_bf16(af[ks], bfv, acc, 0, 0, 0);
      }
      if (n < NVOCAB) {
        #pragma unroll
        for (int r = 0; r < 4; ++r) {
          const int row = rowtile * 16 + quad * 4 + r;
          const int pair = blk * 16 + (row >> 1);
          const int oq = row & 1;
          if (pair < NPAIR)
            table[pair * 226 + oq * NVOCAB + n] = acc[r];
        }
      }
    }
  }
}

// ---------------- Phase C: gather table rows into fp32 output ----------------
__global__ void gather_kernel(const uint32_t* __restrict__ x_raw,
                              const float2* __restrict__ table_v2,
                              float2* __restrict__ out_v2, int total,
                              const int* __restrict__ flags) {
  __shared__ int is64;
  if (threadIdx.x == 0) is64 = flags[1];
  __syncthreads();
  const int i = blockIdx.x * blockDim.x + threadIdx.x;
  if (i >= total) return;
  const int b = i / NVOCAB;
  const int j = i - b * NVOCAB;
  int t0, t1;
  if (is64) {
    t0 = (int)x_raw[4 * b];
    t1 = (int)x_raw[4 * b + 2];
  } else {
    t0 = (int)x_raw[2 * b];
    t1 = (int)x_raw[2 * b + 1];
  }
  t0 = min(max(t0, 0), NVOCAB - 1);
  t1 = min(max(t1, 0), NVOCAB - 1);
  const int pair = t0 * NVOCAB + t1;
  out_v2[i] = table_v2[pair * NVOCAB + j];
}

extern "C" void kernel_launch(void* const* d_in, const int* in_sizes, int n_in,
                              void* d_out, int out_size, void* d_ws, size_t ws_size,
                              hipStream_t stream) {
  // ws layout (byte offsets)
  int*      flags     = (int*)d_ws;                              // 256 B
  float*    wf        = (float*)((char*)d_ws + 256);             // 905728 B
  float*    resid_pre = (float*)((char*)d_ws + 905984);
  float*    qt        = (float*)((char*)d_ws + 1021696);
  float*    kt        = (float*)((char*)d_ws + 1137408);
  float*    vt        = (float*)((char*)d_ws + 1253120);
  float*    table     = (float*)((char*)d_ws + 1368832);         // 11543176 B
  uint16_t* wb        = (uint16_t*)((char*)d_ws + 12912016);     // 327680 B

  const int B = in_sizes[0] / 2;

  detect_kernel<<<1, 256, 0, stream>>>((const uint32_t*)d_in[1],
                                       (const uint32_t*)d_in[0], flags);

  SrcPtrs sp;
  for (int i = 0; i < 11; ++i) sp.p[i] = d_in[i + 1];
  convert_kernel<<<(WTOTAL + 255) / 256, 256, 0, stream>>>(sp, wf, flags);
  transpose_bf16_kernel<<<(BTOTAL + 255) / 256, 256, 0, stream>>>(wf, wb);

  qkv_kernel<<<226, 128, 0, stream>>>(wf, resid_pre, qt, kt, vt);

  const int nblk = (NPAIR + 15) / 16;  // 799
  pair_mfma_kernel<<<nblk, 256, 0, stream>>>(resid_pre, qt, kt, vt, wf, wb,
                                             table);

  const int total = B * NVOCAB;
  gather_kernel<<<(total + 255) / 256, 256, 0, stream>>>(
      (const uint32_t*)d_in[0], (const float2*)table, (float2*)d_out,
      total, flags);
}

// Round 6
// 262.763 us; speedup vs baseline: 5.5399x; 1.0634x over previous
//
#include <hip/hip_runtime.h>
#include <hip/hip_bf16.h>
#include <stdint.h>

typedef __hip_bfloat16 bf16;
typedef __attribute__((ext_vector_type(8))) short short8;
typedef __attribute__((ext_vector_type(4))) float float4v;

#define NVOCAB 113
#define NPAIR (113 * 113)   // 12769
#define DDIM 128
#define HIDDIM 512

// canonical fp32 weight pool element offsets (11 tensors)
#define OFF_TOK 0
#define OFF_POS 14464
#define OFF_WQ  14720
#define OFF_WK  31104
#define OFF_WV  47488
#define OFF_WO  63872
#define OFF_W1  80256
#define OFF_B1  145792
#define OFF_W2  146304
#define OFF_B2  211840
#define OFF_WU  211968
#define WTOTAL  226432

// bf16 transposed weight pool wb (element offsets)
#define BOFF_WOT 0                         // WOT[d][hk] = W_O[hk][d]     128x128
#define BOFF_W1T 16384                     // W1T[n][d]  = W1[d][n]       512x128
#define BOFF_W2T (16384 + 65536)           // W2T[d][j]  = W2[j][d]       128x512
#define BOFF_WUP (16384 + 65536 + 65536)   // WUP[v][d]  = W_U[v][d]|0    128x128
#define BTOTAL   (16384 + 65536 + 65536 + 16384)  // 163840
// qkv transposed weights (live at head of table region, elements)
#define QOFF_Q 0
#define QOFF_K 16384
#define QOFF_V 32768
#define QTOTAL 49152

__device__ __forceinline__ uint16_t f2b(float f) {
  bf16 h = __float2bfloat16(f);
  return *(uint16_t*)&h;
}
__device__ __forceinline__ float b2f(uint16_t u) {
  return __uint_as_float(((uint32_t)u) << 16);
}

// ---------------- runtime dtype detection ----------------
__global__ void detect_kernel(const uint32_t* __restrict__ tok_raw,
                              const uint32_t* __restrict__ x_raw,
                              int* __restrict__ flags) {
  __shared__ int cnt_bf16, cnt_xnz;
  if (threadIdx.x == 0) { cnt_bf16 = 0; cnt_xnz = 0; }
  __syncthreads();
  uint32_t u = tok_raw[threadIdx.x];
  int e = (u >> 7) & 0xff;
  if (e >= 100 && e <= 126) atomicAdd(&cnt_bf16, 1);
  uint32_t xv = x_raw[2 * threadIdx.x + 1];
  if (xv != 0u) atomicAdd(&cnt_xnz, 1);
  __syncthreads();
  if (threadIdx.x == 0) {
    flags[0] = (cnt_bf16 >= 128) ? 1 : 0;   // float tensors are bf16
    flags[1] = (cnt_xnz == 0) ? 1 : 0;      // x is int64
  }
}

// ---------------- canonicalize all float tensors to fp32 pool ----------------
struct SrcPtrs { const void* p[11]; };

__global__ void convert_kernel(SrcPtrs sp, float* __restrict__ dst,
                               const int* __restrict__ flags) {
  const int idx = blockIdx.x * 256 + threadIdx.x;
  if (idx >= WTOTAL) return;
  const int pref[12] = {OFF_TOK, OFF_POS, OFF_WQ, OFF_WK, OFF_WV, OFF_WO,
                        OFF_W1, OFF_B1, OFF_W2, OFF_B2, OFF_WU, WTOTAL};
  int t = 0;
  while (idx >= pref[t + 1]) ++t;
  const int local = idx - pref[t];
  const void* src = sp.p[t];
  if (flags[0]) {
    dst[idx] = __bfloat162float(((const bf16*)src)[local]);
  } else {
    dst[idx] = ((const float*)src)[local];
  }
}

// ---------------- build bf16 transposed weights ----------
__global__ void transpose_bf16_kernel(const float* __restrict__ wf,
                                      uint16_t* __restrict__ wb,
                                      uint16_t* __restrict__ qw) {
  const int idx = blockIdx.x * 256 + threadIdx.x;
  if (idx >= BTOTAL + QTOTAL) return;
  if (idx >= BTOTAL) {
    // QKV: qw[which][h*32+j][d] = W_*[h][d][j]
    int l = idx - BTOTAL;
    int which = l >> 14, r = l & 16383;     // r = (h*32+j)*128 + d
    int hj = r >> 7, d = r & 127;
    int h = hj >> 5, j = hj & 31;
    int off = (which == 0) ? OFF_WQ : (which == 1) ? OFF_WK : OFF_WV;
    qw[l] = f2b(wf[off + h * 4096 + d * 32 + j]);
    return;
  }
  float v;
  if (idx < BOFF_W1T) {                       // WOT[d][c] = W_O[c*128+d]
    int l = idx, d = l >> 7, c = l & 127;
    v = wf[OFF_WO + c * 128 + d];
  } else if (idx < BOFF_W2T) {                // W1T[n][d] = W1[d*512+n]
    int l = idx - BOFF_W1T, n = l >> 7, d = l & 127;
    v = wf[OFF_W1 + d * 512 + n];
  } else if (idx < BOFF_WUP) {                // W2T[d][j] = W2[j*128+d]
    int l = idx - BOFF_W2T, d = l >> 9, j = l & 511;
    v = wf[OFF_W2 + j * 128 + d];
  } else {                                    // WUP[v][d] = W_U[v*128+d] or 0
    int l = idx - BOFF_WUP, vv = l >> 7, d = l & 127;
    v = (vv < NVOCAB) ? wf[OFF_WU + vv * 128 + d] : 0.f;
  }
  wb[idx] = f2b(v);
}

// ---------------- Phase A: embeddings + q/k/v (transposed bf16 weights) -----
// grid: 226 blocks, 384 threads (which q/k/v x 128 outputs)
__global__ void __launch_bounds__(384) qkv_kernel(
    const float* __restrict__ wf, const uint16_t* __restrict__ qw,
    float* __restrict__ resid_pre, float* __restrict__ qt,
    float* __restrict__ kt, float* __restrict__ vt) {
  const int row = blockIdx.x;
  const int t = row >> 1, p = row & 1;
  const int tid = threadIdx.x;

  __shared__ float r[DDIM];
  if (tid < DDIM) {
    float rv = wf[OFF_TOK + t * DDIM + tid] + wf[OFF_POS + p * DDIM + tid];
    r[tid] = rv;
    resid_pre[row * DDIM + tid] = rv;
  }
  __syncthreads();

  const int which = tid >> 7, j = tid & 127;
  const short8* wrow = (const short8*)(qw + which * 16384 + j * 128);
  float a = 0.f;
  #pragma unroll
  for (int ch = 0; ch < 16; ++ch) {
    short8 wv = wrow[ch];
    #pragma unroll
    for (int e = 0; e < 8; ++e)
      a += r[ch * 8 + e] * b2f((uint16_t)wv[e]);
  }
  float* outp = (which == 0) ? qt : (which == 1) ? kt : vt;
  outp[row * DDIM + j] = a;
}

// ---------------- Phase B: fused MFMA kernel, 8 pairs (16 rows) / block -----
// LDS swizzle: element [m][k] at (m*CH + ((k>>3) ^ (m&15)))*8 + (k&7), CH=K/8
// MFMA 16x16x32 bf16 fragment maps (gfx950, m89-verified):
//   A: lane holds A[m=lane&15][k=quad*8+j];  B: lane holds B[k=quad*8+j][n=lane&15]
//   D: reg r = D[row=quad*4+r][col=lane&15]
__global__ void __launch_bounds__(256, 4) pair_mfma_kernel(
    const float* __restrict__ resid_pre, const float* __restrict__ qt,
    const float* __restrict__ kt, const float* __restrict__ vt,
    const float* __restrict__ wf, const uint16_t* __restrict__ wb,
    float* __restrict__ table) {
  __shared__ uint16_t bufH[16 * 512];   // H staging (CH=64), 16 KB
  __shared__ uint16_t bufZ[16 * 128];   // Z, then R (CH=16), 4 KB
  __shared__ uint16_t bufS[16 * 128];   // smid bf16 (CH=16), 4 KB
  __shared__ float    spat[8 * 16];
  __shared__ int      srow[16];

  const int tid = threadIdx.x;
  const int blk = blockIdx.x;

  // ---- prologue: scores ----
  if (tid < 128) {
    const int pl = tid >> 4, s = tid & 15;
    const int pair = blk * 8 + pl;
    if (pair < NPAIR) {
      const int t0 = pair / NVOCAB, t1 = pair - t0 * NVOCAB;
      const int row0 = t0 * 2, row1 = t1 * 2 + 1;
      const int h = s >> 2, qp = (s >> 1) & 1, sp = s & 1;
      const float4* qrow = (const float4*)(qt + (qp ? row1 : row0) * DDIM + h * 32);
      const float4* krow = (const float4*)(kt + (sp ? row1 : row0) * DDIM + h * 32);
      float acc = 0.f;
      #pragma unroll
      for (int j = 0; j < 8; ++j) {
        float4 qv = qrow[j], kv = krow[j];
        acc += qv.x * kv.x + qv.y * kv.y + qv.z * kv.z + qv.w * kv.w;
      }
      spat[pl * 16 + s] = acc * 0.17677669529663687f;
    } else {
      spat[pl * 16 + s] = 0.f;
    }
  } else if (tid < 144) {
    const int m = tid - 128;
    const int pair = blk * 8 + (m >> 1);
    int rv = 0;
    if (pair < NPAIR) {
      const int t0 = pair / NVOCAB, t1 = pair - t0 * NVOCAB;
      rv = (m & 1) ? t1 * 2 + 1 : t0 * 2;
    }
    srow[m] = rv;
  }
  __syncthreads();
  // ---- softmax + blend ----
  if (tid < 64) {
    const int pl = tid >> 3, s = tid & 7;
    const int base = pl * 16 + s * 2;
    float s0 = spat[base], s1 = spat[base + 1];
    float m = fmaxf(s0, s1);
    float e0 = __expf(s0 - m), e1 = __expf(s1 - m);
    float inv = 1.f / (e0 + e1);
    spat[base]     = 0.5f + 0.5f * e0 * inv;
    spat[base + 1] = 0.5f + 0.5f * e1 * inv;
  }
  __syncthreads();
  // ---- Z = pattern-weighted V, staged bf16 ----
  {
    const int m = tid >> 4, c0 = (tid & 15) * 8;
    const int pl = m >> 1, qp = m & 1;
    const int row0 = srow[pl * 2], row1 = srow[pl * 2 + 1];
    const int h = c0 >> 5;
    const float p0 = spat[pl * 16 + h * 4 + qp * 2];
    const float p1 = spat[pl * 16 + h * 4 + qp * 2 + 1];
    short8 pk;
    #pragma unroll
    for (int e = 0; e < 8; ++e) {
      const int c = c0 + e;
      float z = p0 * vt[row0 * DDIM + c] + p1 * vt[row1 * DDIM + c];
      pk[e] = (short)f2b(z);
    }
    *(short8*)&bufZ[(m * 16 + ((c0 >> 3) ^ m)) * 8] = pk;
  }
  __syncthreads();

  const int lane = tid & 63;
  const int npar = tid >> 6;            // wave id = N-partition 0..3
  const int l15 = lane & 15, quad = lane >> 4;
  const int mA = l15;

  float smid[2][4];                     // residual mid kept in registers

  // ---- GEMM0: smid = Z x WOT + resid  (N=128, K=128) ----
  {
    short8 af[4];
    #pragma unroll
    for (int ks = 0; ks < 4; ++ks)
      af[ks] = *(const short8*)&bufZ[(mA * 16 + ((ks * 4 + quad) ^ mA)) * 8];
    #pragma unroll
    for (int ni = 0; ni < 2; ++ni) {
      const int n = (npar + ni * 4) * 16 + l15;
      const uint16_t* bp = wb + BOFF_WOT + n * 128 + quad * 8;
      float4v acc = {0.f, 0.f, 0.f, 0.f};
      #pragma unroll
      for (int ks = 0; ks < 4; ++ks)
        acc = __builtin_amdgcn_mfma_f32_16x16x32_bf16(
            af[ks], *(const short8*)(bp + ks * 32), acc, 0, 0, 0);
      #pragma unroll
      for (int r = 0; r < 4; ++r) {
        const int row = quad * 4 + r;
        float v = acc[r] + resid_pre[srow[row] * DDIM + n];
        smid[ni][r] = v;
        bufS[(row * 16 + ((n >> 3) ^ row)) * 8 + (n & 7)] = f2b(v);
      }
    }
  }
  __syncthreads();

  // ---- GEMM1: H = relu(smid x W1 + b1)  (N=512, K=128) ----
  {
    short8 af[4];
    #pragma unroll
    for (int ks = 0; ks < 4; ++ks)
      af[ks] = *(const short8*)&bufS[(mA * 16 + ((ks * 4 + quad) ^ mA)) * 8];
    #pragma unroll
    for (int ni = 0; ni < 8; ++ni) {
      const int n = (npar + ni * 4) * 16 + l15;
      const uint16_t* bp = wb + BOFF_W1T + n * 128 + quad * 8;
      float4v acc = {0.f, 0.f, 0.f, 0.f};
      #pragma unroll
      for (int ks = 0; ks < 4; ++ks)
        acc = __builtin_amdgcn_mfma_f32_16x16x32_bf16(
            af[ks], *(const short8*)(bp + ks * 32), acc, 0, 0, 0);
      const float bias = wf[OFF_B1 + n];
      #pragma unroll
      for (int r = 0; r < 4; ++r) {
        const int row = quad * 4 + r;
        bufH[(row * 64 + ((n >> 3) ^ row)) * 8 + (n & 7)] =
            f2b(fmaxf(acc[r] + bias, 0.f));
      }
    }
  }
  __syncthreads();

  // ---- GEMM2: R = smid + H x W2 + b2  (N=128, K=512) ----
  {
    short8 ah[16];
    #pragma unroll
    for (int ks = 0; ks < 16; ++ks)
      ah[ks] = *(const short8*)&bufH[(mA * 64 + ((ks * 4 + quad) ^ mA)) * 8];
    #pragma unroll
    for (int ni = 0; ni < 2; ++ni) {
      const int n = (npar + ni * 4) * 16 + l15;
      const uint16_t* bp = wb + BOFF_W2T + n * 512 + quad * 8;
      float4v acc = {0.f, 0.f, 0.f, 0.f};
      #pragma unroll
      for (int ks = 0; ks < 16; ++ks)
        acc = __builtin_amdgcn_mfma_f32_16x16x32_bf16(
            ah[ks], *(const short8*)(bp + ks * 32), acc, 0, 0, 0);
      const float bias = wf[OFF_B2 + n];
      #pragma unroll
      for (int r = 0; r < 4; ++r) {
        const int row = quad * 4 + r;
        bufZ[(row * 16 + ((n >> 3) ^ row)) * 8 + (n & 7)] =
            f2b(acc[r] + bias + smid[ni][r]);
      }
    }
  }
  __syncthreads();

  // ---- GEMM3: logits = R x WUP^T  (N=128 padded, K=128) ----
  {
    short8 ar[4];
    #pragma unroll
    for (int ks = 0; ks < 4; ++ks)
      ar[ks] = *(const short8*)&bufZ[(mA * 16 + ((ks * 4 + quad) ^ mA)) * 8];
    #pragma unroll
    for (int ni = 0; ni < 2; ++ni) {
      const int n = (npar + ni * 4) * 16 + l15;
      const uint16_t* bp = wb + BOFF_WUP + n * 128 + quad * 8;
      float4v acc = {0.f, 0.f, 0.f, 0.f};
      #pragma unroll
      for (int ks = 0; ks < 4; ++ks)
        acc = __builtin_amdgcn_mfma_f32_16x16x32_bf16(
            ar[ks], *(const short8*)(bp + ks * 32), acc, 0, 0, 0);
      if (n < NVOCAB) {
        #pragma unroll
        for (int r = 0; r < 4; ++r) {
          const int row = quad * 4 + r;
          const int pair = blk * 8 + (row >> 1);
          if (pair < NPAIR)
            table[pair * 226 + (row & 1) * NVOCAB + n] = acc[r];
        }
      }
    }
  }
}

// ---------------- Phase C: gather table rows into fp32 output ----------------
__global__ void gather_kernel(const uint32_t* __restrict__ x_raw,
                              const float2* __restrict__ table_v2,
                              float2* __restrict__ out_v2, int total,
                              const int* __restrict__ flags) {
  __shared__ int is64;
  if (threadIdx.x == 0) is64 = flags[1];
  __syncthreads();
  const int i = blockIdx.x * blockDim.x + threadIdx.x;
  if (i >= total) return;
  const int b = i / NVOCAB;
  const int j = i - b * NVOCAB;
  int t0, t1;
  if (is64) {
    t0 = (int)x_raw[4 * b];
    t1 = (int)x_raw[4 * b + 2];
  } else {
    t0 = (int)x_raw[2 * b];
    t1 = (int)x_raw[2 * b + 1];
  }
  t0 = min(max(t0, 0), NVOCAB - 1);
  t1 = min(max(t1, 0), NVOCAB - 1);
  const int pair = t0 * NVOCAB + t1;
  out_v2[i] = table_v2[pair * NVOCAB + j];
}

extern "C" void kernel_launch(void* const* d_in, const int* in_sizes, int n_in,
                              void* d_out, int out_size, void* d_ws, size_t ws_size,
                              hipStream_t stream) {
  // ws layout (byte offsets)
  int*      flags     = (int*)d_ws;                              // 256 B
  float*    wf        = (float*)((char*)d_ws + 256);             // 905728 B
  float*    resid_pre = (float*)((char*)d_ws + 905984);
  float*    qt        = (float*)((char*)d_ws + 1021696);
  float*    kt        = (float*)((char*)d_ws + 1137408);
  float*    vt        = (float*)((char*)d_ws + 1253120);
  float*    table     = (float*)((char*)d_ws + 1368832);         // 11543176 B
  uint16_t* wb        = (uint16_t*)((char*)d_ws + 12912016);     // 327680 B
  // transient: transposed QKV weights live at head of table region
  uint16_t* qw        = (uint16_t*)table;

  const int B = in_sizes[0] / 2;

  detect_kernel<<<1, 256, 0, stream>>>((const uint32_t*)d_in[1],
                                       (const uint32_t*)d_in[0], flags);

  SrcPtrs sp;
  for (int i = 0; i < 11; ++i) sp.p[i] = d_in[i + 1];
  convert_kernel<<<(WTOTAL + 255) / 256, 256, 0, stream>>>(sp, wf, flags);
  transpose_bf16_kernel<<<(BTOTAL + QTOTAL + 255) / 256, 256, 0, stream>>>(
      wf, wb, qw);

  qkv_kernel<<<226, 384, 0, stream>>>(wf, qw, resid_pre, qt, kt, vt);

  const int nblk = (NPAIR + 7) / 8;  // 1597
  pair_mfma_kernel<<<nblk, 256, 0, stream>>>(resid_pre, qt, kt, vt, wf, wb,
                                             table);

  const int total = B * NVOCAB;
  gather_kernel<<<(total + 255) / 256, 256, 0, stream>>>(
      (const uint32_t*)d_in[0], (const float2*)table, (float2*)d_out,
      total, flags);
}